// Round 18
// baseline (47.237 us; speedup 1.0000x reference)
//
#include <hip/hip_runtime.h>
#include <cstdint>
#include <cstddef>

#define NB 20000
#define NT 1000
#define P_PAIRS 50000
#define MARGIN 2.0f
#define RANK_W 0.3f
#define NEG_SENT -1e9f

#define BLOCK 512
#define ROWS_PB 32
#define NBLOCKS (NB / ROWS_PB)      // 625
#define PB4 (P_PAIRS / 4)           // 12500 int4 loads of pair_bacteria
#define PLIST_CAP 512
#define MROW_W 33                   // padded mask words per row

// ---------------- workspace layout ----------------
// [0, 10000) float4 partials[625] -- fully overwritten every call.

// branchless sorted-desc insert of x into (t0>=t1>=t2>=t3>=t4)
#define INSERT5(x)                                        \
    {                                                     \
        float _x = (x);                                   \
        float n0 = fmaxf(t0, _x), s0_ = fminf(t0, _x);    \
        float n1 = fmaxf(t1, s0_), s1_ = fminf(t1, s0_);  \
        float n2 = fmaxf(t2, s1_), s2_ = fminf(t2, s1_);  \
        float n3 = fmaxf(t3, s2_), s3_ = fminf(t3, s2_);  \
        float n4 = fmaxf(t4, s3_);                        \
        t0 = n0; t1 = n1; t2 = n2; t3 = n3; t4 = n4;      \
    }

#define PROC1(xv, lab)                                              \
    {                                                               \
        float _x = (xv);                                            \
        int _lab = (lab);                                           \
        float _s = __builtin_amdgcn_rcpf(1.0f + __expf(-_x));       \
        float _d = (float)_lab - _s;                                \
        sq = fmaf(_d, _d, sq);                                      \
        pcount += _lab;                                             \
        float _xx = _lab ? NEG_SENT : _x;                           \
        INSERT5(_xx);                                               \
    }

#define PROC4(v, bits)                        \
    PROC1((v).x, (int)(((bits) >> 0) & 1u));  \
    PROC1((v).y, (int)(((bits) >> 1) & 1u));  \
    PROC1((v).z, (int)(((bits) >> 2) & 1u));  \
    PROC1((v).w, (int)(((bits) >> 3) & 1u));

// scan-check 4 pair_bacteria entries; on match set LDS mask bit + record pair
#define SCAN4(v, idx)                                                   \
    {                                                                   \
        int _bs[4] = {(v).x, (v).y, (v).z, (v).w};                      \
        _Pragma("unroll")                                               \
        for (int _j = 0; _j < 4; ++_j) {                                \
            unsigned int _d = (unsigned int)(_bs[_j] - rowBase);        \
            if (_d < (unsigned int)ROWS_PB) {                           \
                int _t = pt[(idx) * 4 + _j];                            \
                atomicOr(&smask[_d * MROW_W + (_t >> 5)], 1u << (_t & 31)); \
                int _k = atomicAdd(&pcnt, 1);                           \
                if (_k < PLIST_CAP) plist[_k] = ((int)_d << 10) | _t;   \
            }                                                           \
        }                                                               \
    }

// issue one 16B row load NOW (asm volatile: compiler cannot sink it past the
// scan the way it sank R11's plain loads). Result lands before the post-scan
// barrier's vmcnt(0) drain.
#define EARLY_LOAD(reg, fofs)                                            \
    asm volatile("global_load_dwordx4 %0, %1, off"                       \
                 : "=v"(reg) : "v"(rowp + gl + (fofs)));

// K1: 32 rows per 512-thread block (625 blocks). 12/16 row loads issued
// before the pair scan (HBM stream overlaps L2 scan); mask from LDS;
// fence-free float4 partials store.
__global__ __launch_bounds__(BLOCK)
void fused_row_pair_kernel(const float* __restrict__ scores,
                           const int* __restrict__ pb,
                           const int* __restrict__ pt,
                           float4* __restrict__ partials) {
    const int tid  = threadIdx.x;
    const int lane = tid & 63;
    const int wib  = tid >> 6;          // wave in block 0..7
    const int grp  = lane >> 4;         // group in wave  0..3
    const int gl   = lane & 15;         // lane in group  0..15
    const int rowBase = blockIdx.x * ROWS_PB;

    __shared__ unsigned int smask[ROWS_PB * MROW_W];   // 1056 words
    __shared__ float  stop5[ROWS_PB][5];
    __shared__ int    snn[ROWS_PB];
    __shared__ int    plist[PLIST_CAP];
    __shared__ int    pcnt;
    __shared__ float  bsq[ROWS_PB];
    __shared__ float  sc[8];
    __shared__ unsigned int sv[8];

    // ---- Phase 1: zero LDS mask + counter ----
    for (int i = tid; i < ROWS_PB * MROW_W; i += BLOCK) smask[i] = 0u;
    if (tid == 0) pcnt = 0;
    __syncthreads();

    // ---- Phase 1.5: force-issue 12 of 16 row loads (48 VGPRs live) ----
    const int localRow = wib * 4 + grp;          // 0..31
    const int row = rowBase + localRow;
    const float4* rowp = reinterpret_cast<const float4*>(scores + (size_t)row * NT);
    float4 s0, s1, s2, s3, s4, s5, s6, s7, s8, s9, s10, s11;
    EARLY_LOAD(s0,    0); EARLY_LOAD(s1,   16); EARLY_LOAD(s2,   32);
    EARLY_LOAD(s3,   48); EARLY_LOAD(s4,   64); EARLY_LOAD(s5,   80);
    EARLY_LOAD(s6,   96); EARLY_LOAD(s7,  112); EARLY_LOAD(s8,  128);
    EARLY_LOAD(s9,  144); EARLY_LOAD(s10, 160); EARLY_LOAD(s11, 176);

    // ---- Phase 2: pair scan (4-deep batched), overlapped with the loads ----
    const int4* pb4 = reinterpret_cast<const int4*>(pb);
    #pragma unroll 1
    for (int base = tid; base + 1536 < PB4; base += 2048) {
        int4 va = pb4[base       ];
        int4 vb = pb4[base +  512];
        int4 vc = pb4[base + 1024];
        int4 vd = pb4[base + 1536];
        SCAN4(va, base);
        SCAN4(vb, base +  512);
        SCAN4(vc, base + 1024);
        SCAN4(vd, base + 1536);
    }
    {   // tail: indices 12288 .. 12499
        int idx = 12288 + tid;
        if (idx < PB4) {
            int4 v = pb4[idx];
            SCAN4(v, idx);
        }
    }
    __syncthreads();                               // drains vmcnt -> s0..s11 valid
    asm volatile("s_waitcnt vmcnt(0)" ::: "memory");

    // ---- Phase 3: row pass (16 lanes/row; mask from LDS) ----
    const unsigned int* mrow = smask + localRow * MROW_W;
    const int wb = gl >> 3;
    const int sh = (gl & 7) * 4;

    float t0 = NEG_SENT, t1 = NEG_SENT, t2 = NEG_SENT, t3 = NEG_SENT, t4 = NEG_SENT;
    float sq = 0.0f;
    int pcount = 0;

    {
        unsigned int b0  = (mrow[wb     ] >> sh) & 0xFu;
        unsigned int b1  = (mrow[wb +  2] >> sh) & 0xFu;
        unsigned int b2  = (mrow[wb +  4] >> sh) & 0xFu;
        unsigned int b3  = (mrow[wb +  6] >> sh) & 0xFu;
        unsigned int b4  = (mrow[wb +  8] >> sh) & 0xFu;
        unsigned int b5  = (mrow[wb + 10] >> sh) & 0xFu;
        unsigned int b6  = (mrow[wb + 12] >> sh) & 0xFu;
        unsigned int b7  = (mrow[wb + 14] >> sh) & 0xFu;
        unsigned int b8  = (mrow[wb + 16] >> sh) & 0xFu;
        unsigned int b9  = (mrow[wb + 18] >> sh) & 0xFu;
        unsigned int b10 = (mrow[wb + 20] >> sh) & 0xFu;
        unsigned int b11 = (mrow[wb + 22] >> sh) & 0xFu;
        PROC4(s0, b0);  PROC4(s1, b1);  PROC4(s2, b2);  PROC4(s3, b3);
        PROC4(s4, b4);  PROC4(s5, b5);  PROC4(s6, b6);  PROC4(s7, b7);
        PROC4(s8, b8);  PROC4(s9, b9);  PROC4(s10, b10); PROC4(s11, b11);
    }
    {   // k = 12..14 (normal loads; L2/HBM, short)
        float4 v0 = rowp[gl + 192];
        float4 v1 = rowp[gl + 208];
        float4 v2 = rowp[gl + 224];
        unsigned int b0 = (mrow[wb + 24] >> sh) & 0xFu;
        unsigned int b1 = (mrow[wb + 26] >> sh) & 0xFu;
        unsigned int b2 = (mrow[wb + 28] >> sh) & 0xFu;
        PROC4(v0, b0); PROC4(v1, b1); PROC4(v2, b2);
    }
    if (gl < 10) {   // k = 15 tail (250 float4 per row)
        float4 v = rowp[gl + 240];
        unsigned int bt = (mrow[wb + 30] >> sh) & 0xFu;
        PROC4(v, bt);
    }

    #pragma unroll
    for (int off = 8; off >= 1; off >>= 1) {
        float b0 = __shfl_xor(t0, off, 16);
        float b1 = __shfl_xor(t1, off, 16);
        float b2 = __shfl_xor(t2, off, 16);
        float b3 = __shfl_xor(t3, off, 16);
        float b4 = __shfl_xor(t4, off, 16);
        sq     += __shfl_xor(sq, off, 16);
        pcount += __shfl_xor(pcount, off, 16);

        float m1  = fminf(t0, b0);
        float m2a = fminf(t1, b0), m2b = fminf(t0, b1);
        float m3a = fminf(t2, b0), m3b = fminf(t1, b1), m3c = fminf(t0, b2);
        float m4a = fminf(t3, b0), m4b = fminf(t2, b1), m4c = fminf(t1, b2), m4d = fminf(t0, b3);
        float c0 = fmaxf(t0, b0);
        float c1 = fmaxf(fmaxf(t1, b1), m1);
        float c2 = fmaxf(fmaxf(t2, b2), fmaxf(m2a, m2b));
        float c3 = fmaxf(fmaxf(t3, b3), fmaxf(fmaxf(m3a, m3b), m3c));
        float c4 = fmaxf(fmaxf(t4, b4), fmaxf(fmaxf(m4a, m4b), fmaxf(m4c, m4d)));
        t0 = c0; t1 = c1; t2 = c2; t3 = c3; t4 = c4;
    }

    if (gl == 0) {
        stop5[localRow][0] = t0; stop5[localRow][1] = t1; stop5[localRow][2] = t2;
        stop5[localRow][3] = t3; stop5[localRow][4] = t4;
        snn[localRow] = NT - pcount;
        bsq[localRow] = sq;
    }
    __syncthreads();

    // ---- Phase 4: this block's pair contributions ----
    float c = 0.0f;
    unsigned int valid = 0;
    int np = pcnt;
    if (np <= PLIST_CAP) {
        for (int k = tid; k < np; k += BLOCK) {
            int e = plist[k];
            int lr = e >> 10, t = e & 1023;
            float pos = scores[(size_t)(rowBase + lr) * NT + t];
            #pragma unroll
            for (int q = 0; q < 5; ++q) {
                float contrib = MARGIN - (pos - stop5[lr][q]);
                c += contrib > 0.0f ? contrib : 0.0f;
            }
            int nn = snn[lr];
            valid += (unsigned int)(nn < 5 ? nn : 5);
        }
    } else {
        // overflow fallback: rescan pair list (never taken for this dataset)
        for (int i = tid; i < PB4; i += BLOCK) {
            int4 v = pb4[i];
            int bs[4] = {v.x, v.y, v.z, v.w};
            #pragma unroll
            for (int j = 0; j < 4; ++j) {
                unsigned int d = (unsigned int)(bs[j] - rowBase);
                if (d < (unsigned int)ROWS_PB) {
                    int t = pt[i * 4 + j];
                    float pos = scores[(size_t)(rowBase + d) * NT + t];
                    #pragma unroll
                    for (int q = 0; q < 5; ++q) {
                        float contrib = MARGIN - (pos - stop5[d][q]);
                        c += contrib > 0.0f ? contrib : 0.0f;
                    }
                    int nn = snn[d];
                    valid += (unsigned int)(nn < 5 ? nn : 5);
                }
            }
        }
    }

    #pragma unroll
    for (int off = 32; off >= 1; off >>= 1) {
        c     += __shfl_xor(c, off);
        valid += __shfl_xor(valid, off);
    }
    if ((tid & 63) == 0) { sc[wib] = c; sv[wib] = valid; }
    __syncthreads();
    if (tid == 0) {
        float s = 0.0f;
        #pragma unroll
        for (int k = 0; k < ROWS_PB; ++k) s += bsq[k];
        float cb = 0.0f;
        float vb = 0.0f;
        #pragma unroll
        for (int w = 0; w < 8; ++w) { cb += sc[w]; vb += (float)sv[w]; }
        partials[blockIdx.x] = make_float4(s, cb, vb, 0.0f);
    }
}

// K2: single-block reduction of 625 partials -> loss
__global__ __launch_bounds__(256)
void finalize_kernel(const float4* __restrict__ partials,
                     float* __restrict__ out) {
    float s = 0.0f, cb = 0.0f, vb = 0.0f;
    for (int i = threadIdx.x; i < NBLOCKS; i += 256) {
        float4 p = partials[i];
        s += p.x; cb += p.y; vb += p.z;
    }
    #pragma unroll
    for (int off = 32; off >= 1; off >>= 1) {
        s  += __shfl_xor(s, off);
        cb += __shfl_xor(cb, off);
        vb += __shfl_xor(vb, off);
    }
    __shared__ float ss[4], scc[4], svv[4];
    int wib = threadIdx.x >> 6;
    if ((threadIdx.x & 63) == 0) { ss[wib] = s; scc[wib] = cb; svv[wib] = vb; }
    __syncthreads();
    if (threadIdx.x == 0) {
        float st = ss[0] + ss[1] + ss[2] + ss[3];
        float ct = scc[0] + scc[1] + scc[2] + scc[3];
        float vt = svv[0] + svv[1] + svv[2] + svv[3];
        float loss = 0.5f * st / 2.0e7f;            // NB*NT = 2e7
        if (vt > 0.0f) loss += RANK_W * ct / vt;
        out[0] = loss;
    }
}

extern "C" void kernel_launch(void* const* d_in, const int* in_sizes, int n_in,
                              void* d_out, int out_size, void* d_ws, size_t ws_size,
                              hipStream_t stream) {
    const float* scores = (const float*)d_in[0];
    const int*   pb     = (const int*)d_in[1];
    const int*   pt     = (const int*)d_in[2];
    float*       out    = (float*)d_out;
    float4*      partials = (float4*)d_ws;

    fused_row_pair_kernel<<<NBLOCKS, BLOCK, 0, stream>>>(scores, pb, pt, partials);
    finalize_kernel<<<1, 256, 0, stream>>>(partials, out);
}

// Round 19
// 31.940 us; speedup vs baseline: 1.4789x; 1.4789x over previous
//
#include <hip/hip_runtime.h>
#include <cstdint>
#include <cstddef>

#define NB 20000
#define NT 1000
#define P_PAIRS 50000
#define MARGIN 2.0f
#define RANK_W 0.3f
#define NEG_SENT -1e9f

#define BLOCK 1024
#define ROWS_PB 80
#define NBLOCKS (NB / ROWS_PB)      // 250 <= 256 CUs -> exactly 1 block/CU
#define PB4 (P_PAIRS / 4)           // 12500 int4 loads of pair_bacteria
#define PLIST_CAP 512               // expected ~200 pairs/block (22 sigma margin)
#define MROW_W 33                   // padded mask words per row

// ---------------- workspace layout ----------------
// [0, 4000) float4 partials[250] -- fully overwritten every call.

// branchless sorted-desc insert of x into (t0>=t1>=t2>=t3>=t4)
#define INSERT5(x)                                        \
    {                                                     \
        float _x = (x);                                   \
        float n0 = fmaxf(t0, _x), s0_ = fminf(t0, _x);    \
        float n1 = fmaxf(t1, s0_), s1_ = fminf(t1, s0_);  \
        float n2 = fmaxf(t2, s1_), s2_ = fminf(t2, s1_);  \
        float n3 = fmaxf(t3, s2_), s3_ = fminf(t3, s2_);  \
        float n4 = fmaxf(t4, s3_);                        \
        t0 = n0; t1 = n1; t2 = n2; t3 = n3; t4 = n4;      \
    }

#define PROC1(xv, lab)                                              \
    {                                                               \
        float _x = (xv);                                            \
        int _lab = (lab);                                           \
        float _s = __builtin_amdgcn_rcpf(1.0f + __expf(-_x));       \
        float _d = (float)_lab - _s;                                \
        sq = fmaf(_d, _d, sq);                                      \
        pcount += _lab;                                             \
        float _xx = _lab ? NEG_SENT : _x;                           \
        INSERT5(_xx);                                               \
    }

#define PROC4(v, bits)                        \
    PROC1((v).x, (int)(((bits) >> 0) & 1u));  \
    PROC1((v).y, (int)(((bits) >> 1) & 1u));  \
    PROC1((v).z, (int)(((bits) >> 2) & 1u));  \
    PROC1((v).w, (int)(((bits) >> 3) & 1u));

// scan-check 4 pair_bacteria entries; on match set LDS mask bit + record pair
#define SCAN4(v, idx)                                                   \
    {                                                                   \
        int _bs[4] = {(v).x, (v).y, (v).z, (v).w};                      \
        _Pragma("unroll")                                               \
        for (int _j = 0; _j < 4; ++_j) {                                \
            unsigned int _d = (unsigned int)(_bs[_j] - rowBase);        \
            if (_d < (unsigned int)ROWS_PB) {                           \
                int _t = pt[(idx) * 4 + _j];                            \
                atomicOr(&smask[_d * MROW_W + (_t >> 5)], 1u << (_t & 31)); \
                int _k = atomicAdd(&pcnt, 1);                           \
                if (_k < PLIST_CAP) plist[_k] = ((int)_d << 10) | _t;   \
            }                                                           \
        }                                                               \
    }

// K1: 80 rows per 1024-thread block, 250 blocks = 1 block/CU (perfect
// balance; worst-CU scan work 600KB->200KB vs R12). Plain loads, fence-free
// partials store (R12-proven pattern).
__global__ __launch_bounds__(BLOCK)
void fused_row_pair_kernel(const float* __restrict__ scores,
                           const int* __restrict__ pb,
                           const int* __restrict__ pt,
                           float4* __restrict__ partials) {
    const int tid  = threadIdx.x;
    const int lane = tid & 63;
    const int wib  = tid >> 6;          // wave in block 0..15
    const int grp  = lane >> 4;         // group in wave  0..3
    const int gl   = lane & 15;         // lane in group  0..15
    const int gslot = wib * 4 + grp;    // group slot 0..63
    const int rowBase = blockIdx.x * ROWS_PB;

    __shared__ unsigned int smask[ROWS_PB * MROW_W];   // 2640 words = 10560 B
    __shared__ float  stop5[ROWS_PB][5];
    __shared__ int    snn[ROWS_PB];
    __shared__ int    plist[PLIST_CAP];
    __shared__ int    pcnt;
    __shared__ float  bsq[ROWS_PB];
    __shared__ float  sc[16];
    __shared__ unsigned int sv[16];

    // ---- Phase 1: zero LDS mask + counter ----
    for (int i = tid; i < ROWS_PB * MROW_W; i += BLOCK) smask[i] = 0u;
    if (tid == 0) pcnt = 0;
    __syncthreads();

    // ---- Phase 2: pair scan (3 uniform 4-deep batches + tail) ----
    const int4* pb4 = reinterpret_cast<const int4*>(pb);
    #pragma unroll 1
    for (int base = tid; base + 3072 < PB4; base += 4096) {
        int4 va = pb4[base       ];
        int4 vb = pb4[base + 1024];
        int4 vc = pb4[base + 2048];
        int4 vd = pb4[base + 3072];
        SCAN4(va, base);
        SCAN4(vb, base + 1024);
        SCAN4(vc, base + 2048);
        SCAN4(vd, base + 3072);
    }
    {   // tail: indices 12288 .. 12499
        int idx = 12288 + tid;
        if (idx < PB4) {
            int4 v = pb4[idx];
            SCAN4(v, idx);
        }
    }
    __syncthreads();

    const int wb = gl >> 3;
    const int sh = (gl & 7) * 4;

    // ---- Phase 3: row pass. 64 group-slots x 2 passes cover 80 rows ----
    #pragma unroll 1
    for (int p = 0; p < 2; ++p) {
        const int localRow = p * 64 + gslot;
        if (localRow >= ROWS_PB) break;          // pass 2: only wib<4 active
        const int row = rowBase + localRow;
        const float4* rowp = reinterpret_cast<const float4*>(scores + (size_t)row * NT);
        const unsigned int* mrow = smask + localRow * MROW_W;

        float t0 = NEG_SENT, t1 = NEG_SENT, t2 = NEG_SENT, t3 = NEG_SENT, t4 = NEG_SENT;
        float sq = 0.0f;
        int pcount = 0;

        {
            float4 v0 = rowp[gl      ];
            float4 v1 = rowp[gl +  16];
            float4 v2 = rowp[gl +  32];
            float4 v3 = rowp[gl +  48];
            unsigned int b0 = (mrow[wb     ] >> sh) & 0xFu;
            unsigned int b1 = (mrow[wb +  2] >> sh) & 0xFu;
            unsigned int b2 = (mrow[wb +  4] >> sh) & 0xFu;
            unsigned int b3 = (mrow[wb +  6] >> sh) & 0xFu;
            PROC4(v0, b0); PROC4(v1, b1); PROC4(v2, b2); PROC4(v3, b3);
        }
        {
            float4 v0 = rowp[gl +  64];
            float4 v1 = rowp[gl +  80];
            float4 v2 = rowp[gl +  96];
            float4 v3 = rowp[gl + 112];
            unsigned int b0 = (mrow[wb +  8] >> sh) & 0xFu;
            unsigned int b1 = (mrow[wb + 10] >> sh) & 0xFu;
            unsigned int b2 = (mrow[wb + 12] >> sh) & 0xFu;
            unsigned int b3 = (mrow[wb + 14] >> sh) & 0xFu;
            PROC4(v0, b0); PROC4(v1, b1); PROC4(v2, b2); PROC4(v3, b3);
        }
        {
            float4 v0 = rowp[gl + 128];
            float4 v1 = rowp[gl + 144];
            float4 v2 = rowp[gl + 160];
            float4 v3 = rowp[gl + 176];
            unsigned int b0 = (mrow[wb + 16] >> sh) & 0xFu;
            unsigned int b1 = (mrow[wb + 18] >> sh) & 0xFu;
            unsigned int b2 = (mrow[wb + 20] >> sh) & 0xFu;
            unsigned int b3 = (mrow[wb + 22] >> sh) & 0xFu;
            PROC4(v0, b0); PROC4(v1, b1); PROC4(v2, b2); PROC4(v3, b3);
        }
        {
            float4 v0 = rowp[gl + 192];
            float4 v1 = rowp[gl + 208];
            float4 v2 = rowp[gl + 224];
            unsigned int b0 = (mrow[wb + 24] >> sh) & 0xFu;
            unsigned int b1 = (mrow[wb + 26] >> sh) & 0xFu;
            unsigned int b2 = (mrow[wb + 28] >> sh) & 0xFu;
            PROC4(v0, b0); PROC4(v1, b1); PROC4(v2, b2);
        }
        if (gl < 10) {   // tail (250 float4 per row)
            float4 v = rowp[gl + 240];
            unsigned int bt = (mrow[wb + 30] >> sh) & 0xFu;
            PROC4(v, bt);
        }

        #pragma unroll
        for (int off = 8; off >= 1; off >>= 1) {
            float b0 = __shfl_xor(t0, off, 16);
            float b1 = __shfl_xor(t1, off, 16);
            float b2 = __shfl_xor(t2, off, 16);
            float b3 = __shfl_xor(t3, off, 16);
            float b4 = __shfl_xor(t4, off, 16);
            sq     += __shfl_xor(sq, off, 16);
            pcount += __shfl_xor(pcount, off, 16);

            float m1  = fminf(t0, b0);
            float m2a = fminf(t1, b0), m2b = fminf(t0, b1);
            float m3a = fminf(t2, b0), m3b = fminf(t1, b1), m3c = fminf(t0, b2);
            float m4a = fminf(t3, b0), m4b = fminf(t2, b1), m4c = fminf(t1, b2), m4d = fminf(t0, b3);
            float c0 = fmaxf(t0, b0);
            float c1 = fmaxf(fmaxf(t1, b1), m1);
            float c2 = fmaxf(fmaxf(t2, b2), fmaxf(m2a, m2b));
            float c3 = fmaxf(fmaxf(t3, b3), fmaxf(fmaxf(m3a, m3b), m3c));
            float c4 = fmaxf(fmaxf(t4, b4), fmaxf(fmaxf(m4a, m4b), fmaxf(m4c, m4d)));
            t0 = c0; t1 = c1; t2 = c2; t3 = c3; t4 = c4;
        }

        if (gl == 0) {
            stop5[localRow][0] = t0; stop5[localRow][1] = t1; stop5[localRow][2] = t2;
            stop5[localRow][3] = t3; stop5[localRow][4] = t4;
            snn[localRow] = NT - pcount;
            bsq[localRow] = sq;
        }
    }
    __syncthreads();

    // ---- Phase 4: this block's pair contributions ----
    float c = 0.0f;
    unsigned int valid = 0;
    int np = pcnt;
    if (np <= PLIST_CAP) {
        for (int k = tid; k < np; k += BLOCK) {
            int e = plist[k];
            int lr = e >> 10, t = e & 1023;
            float pos = scores[(size_t)(rowBase + lr) * NT + t];
            #pragma unroll
            for (int q = 0; q < 5; ++q) {
                float contrib = MARGIN - (pos - stop5[lr][q]);
                c += contrib > 0.0f ? contrib : 0.0f;
            }
            int nn = snn[lr];
            valid += (unsigned int)(nn < 5 ? nn : 5);
        }
    } else {
        // overflow fallback: rescan pair list (never taken for this dataset)
        for (int i = tid; i < PB4; i += BLOCK) {
            int4 v = pb4[i];
            int bs[4] = {v.x, v.y, v.z, v.w};
            #pragma unroll
            for (int j = 0; j < 4; ++j) {
                unsigned int d = (unsigned int)(bs[j] - rowBase);
                if (d < (unsigned int)ROWS_PB) {
                    int t = pt[i * 4 + j];
                    float pos = scores[(size_t)(rowBase + d) * NT + t];
                    #pragma unroll
                    for (int q = 0; q < 5; ++q) {
                        float contrib = MARGIN - (pos - stop5[d][q]);
                        c += contrib > 0.0f ? contrib : 0.0f;
                    }
                    int nn = snn[d];
                    valid += (unsigned int)(nn < 5 ? nn : 5);
                }
            }
        }
    }

    #pragma unroll
    for (int off = 32; off >= 1; off >>= 1) {
        c     += __shfl_xor(c, off);
        valid += __shfl_xor(valid, off);
    }
    if ((tid & 63) == 0) { sc[wib] = c; sv[wib] = valid; }
    __syncthreads();
    if (tid == 0) {
        float s = 0.0f;
        #pragma unroll
        for (int k = 0; k < ROWS_PB; ++k) s += bsq[k];
        float cb = 0.0f;
        float vb = 0.0f;
        #pragma unroll
        for (int w = 0; w < 16; ++w) { cb += sc[w]; vb += (float)sv[w]; }
        partials[blockIdx.x] = make_float4(s, cb, vb, 0.0f);
    }
}

// K2: single-block reduction of 250 partials -> loss
__global__ __launch_bounds__(256)
void finalize_kernel(const float4* __restrict__ partials,
                     float* __restrict__ out) {
    float s = 0.0f, cb = 0.0f, vb = 0.0f;
    for (int i = threadIdx.x; i < NBLOCKS; i += 256) {
        float4 p = partials[i];
        s += p.x; cb += p.y; vb += p.z;
    }
    #pragma unroll
    for (int off = 32; off >= 1; off >>= 1) {
        s  += __shfl_xor(s, off);
        cb += __shfl_xor(cb, off);
        vb += __shfl_xor(vb, off);
    }
    __shared__ float ss[4], scc[4], svv[4];
    int wib = threadIdx.x >> 6;
    if ((threadIdx.x & 63) == 0) { ss[wib] = s; scc[wib] = cb; svv[wib] = vb; }
    __syncthreads();
    if (threadIdx.x == 0) {
        float st = ss[0] + ss[1] + ss[2] + ss[3];
        float ct = scc[0] + scc[1] + scc[2] + scc[3];
        float vt = svv[0] + svv[1] + svv[2] + svv[3];
        float loss = 0.5f * st / 2.0e7f;            // NB*NT = 2e7
        if (vt > 0.0f) loss += RANK_W * ct / vt;
        out[0] = loss;
    }
}

extern "C" void kernel_launch(void* const* d_in, const int* in_sizes, int n_in,
                              void* d_out, int out_size, void* d_ws, size_t ws_size,
                              hipStream_t stream) {
    const float* scores = (const float*)d_in[0];
    const int*   pb     = (const int*)d_in[1];
    const int*   pt     = (const int*)d_in[2];
    float*       out    = (float*)d_out;
    float4*      partials = (float4*)d_ws;

    fused_row_pair_kernel<<<NBLOCKS, BLOCK, 0, stream>>>(scores, pb, pt, partials);
    finalize_kernel<<<1, 256, 0, stream>>>(partials, out);
}